// Round 4
// baseline (1099.730 us; speedup 1.0000x reference)
//
#include <hip/hip_runtime.h>
#include <hip/hip_bf16.h>

// ---- problem constants ----
#define NTOK_B   32768      // tokens per batch (H*W*D)
#define TOK_TOT  65536      // B * NTOK_B
#define CDIM     256
#define NHEAD    8
#define DHEAD    32
#define FFDIM    1024
#define LN_EPS   1e-3f

typedef __attribute__((ext_vector_type(8))) short bf16x8;   // 8 bf16 in 4 VGPRs
typedef __attribute__((ext_vector_type(4))) float f32x4;

__device__ __forceinline__ float bf2f(short s) {
    union { unsigned u; float f; } v; v.u = ((unsigned)(unsigned short)s) << 16; return v.f;
}
__device__ __forceinline__ short f2bf(float f) {
    union { float f; unsigned u; } v; v.f = f;
    unsigned r = (v.u + 0x7FFFu + ((v.u >> 16) & 1u)) >> 16;
    return (short)r;
}

// ---------------------------------------------------------------------------
// fp32 -> bf16 bulk convert (8 elements/thread)
// ---------------------------------------------------------------------------
__global__ __launch_bounds__(256) void cvt_bf16_k(const float* __restrict__ in,
                                                  short* __restrict__ out)
{
    long i = ((long)blockIdx.x * 256 + threadIdx.x) * 8;
    float4 a = *(const float4*)(in + i);
    float4 b = *(const float4*)(in + i + 4);
    short t[8];
    t[0] = f2bf(a.x); t[1] = f2bf(a.y); t[2] = f2bf(a.z); t[3] = f2bf(a.w);
    t[4] = f2bf(b.x); t[5] = f2bf(b.y); t[6] = f2bf(b.z); t[7] = f2bf(b.w);
    *(int4*)(out + i) = *(const int4*)t;
}

// ---------------------------------------------------------------------------
// Weight transpose + fp32->bf16: out[n][k] = bf16(in[k][n]). K,N multiples of 32.
// ---------------------------------------------------------------------------
__global__ __launch_bounds__(256) void transpose_k(const float* __restrict__ in,
                                                   short* __restrict__ out, int K, int N)
{
    __shared__ float t[32][33];
    int kt = blockIdx.x * 32, nt = blockIdx.y * 32;
    int tx = threadIdx.x, ty = threadIdx.y;          // blockDim = (32,8)
#pragma unroll
    for (int i = 0; i < 4; ++i)
        t[ty + i * 8][tx] = in[(long)(kt + ty + i * 8) * N + nt + tx];
    __syncthreads();
#pragma unroll
    for (int i = 0; i < 4; ++i)
        out[(long)(nt + ty + i * 8) * K + kt + tx] = f2bf(t[tx][ty + i * 8]);
}

__global__ void concat_bias(const float* __restrict__ a, const float* __restrict__ b,
                            float* __restrict__ o)
{
    int t = threadIdx.x;
    o[t] = a[t]; o[t + 256] = b[t];
}

// ---------------------------------------------------------------------------
// MFMA GEMM: Out[M][N] = act(X[M][K](bf16, ld=ldx) @ Wt[N][K]^T + bias(f32))
// Out fp32 (OF32=1) or bf16 (OF32=0). ACT: 0 none, 1 exact GELU.
// 128x128 tile, BK=64 (two k-steps of 32), 4 waves x 4x4 tiles of
// mfma_f32_16x16x32_bf16. LDS fragment order: chunk c = (s*8+ti)*64 + lane,
// 16B each; staged by thread tid as chunks tid + p*256 (p=0..3) -> both
// ds_write_b128 and ds_read_b128 are stride-1 (2-way aliasing = free, m136).
// Global loads are issued BEFORE the barrier (register prefetch in flight
// across it). A-frag: A[m=lane&15][k=(lane>>4)*8+j]; C/D: col=lane&15,
// row=(lane>>4)*4+r (m89/m91-verified). Grid: (N/128, M/128), 256 threads.
// K must be a multiple of 64.
// ---------------------------------------------------------------------------
template<int ACT, int OF32>
__global__ __launch_bounds__(256) void gemm_bt(const short* __restrict__ X,
                                               const short* __restrict__ Wt,
                                               const float* __restrict__ bias,
                                               void* __restrict__ Outv,
                                               int N, int K, int ldx, int ldo)
{
    __shared__ __align__(16) short As[8192];   // 16 KB: 128 rows x 64 k
    __shared__ __align__(16) short Bs[8192];
    const int tid  = threadIdx.x;
    const int lane = tid & 63;
    const int wave = tid >> 6;
    const int wm   = (wave >> 1) * 4;
    const int wn   = (wave & 1) * 4;
    const long m0  = (long)blockIdx.y * 128;
    const int  n0  = blockIdx.x * 128;

    // staging pointers: chunk c = tid + p*256; st = wave + p*4; s=st>>3, ti=st&7
    const int m_ = lane & 15, q8 = (lane >> 4) * 8;
    const short* gA[4]; const short* gB[4];
    short* lA[4]; short* lB[4];
#pragma unroll
    for (int p = 0; p < 4; ++p) {
        int st = wave + p * 4, s = st >> 3, ti = st & 7;
        gA[p] = X  + (m0 + ti * 16 + m_) * (long)ldx + s * 32 + q8;
        gB[p] = Wt + (long)(n0 + ti * 16 + m_) * K   + s * 32 + q8;
        lA[p] = As + (st * 64 + lane) * 8;
        lB[p] = Bs + (st * 64 + lane) * 8;
    }

    f32x4 acc[4][4];
#pragma unroll
    for (int i = 0; i < 4; ++i)
#pragma unroll
        for (int j = 0; j < 4; ++j) acc[i][j] = (f32x4)0.0f;

    for (int k0 = 0; k0 < K; k0 += 64) {
        int4 av[4], bv[4];
#pragma unroll
        for (int p = 0; p < 4; ++p) {
            av[p] = *(const int4*)gA[p]; gA[p] += 64;
            bv[p] = *(const int4*)gB[p]; gB[p] += 64;
        }
        __syncthreads();                 // previous iter's LDS reads done
#pragma unroll
        for (int p = 0; p < 4; ++p) {
            *(int4*)lA[p] = av[p];
            *(int4*)lB[p] = bv[p];
        }
        __syncthreads();
#pragma unroll
        for (int s = 0; s < 2; ++s) {
            bf16x8 a[4], b[4];
#pragma unroll
            for (int i = 0; i < 4; ++i)
                a[i] = *(const bf16x8*)(As + ((s * 8 + wm + i) * 64 + lane) * 8);
#pragma unroll
            for (int j = 0; j < 4; ++j)
                b[j] = *(const bf16x8*)(Bs + ((s * 8 + wn + j) * 64 + lane) * 8);
#pragma unroll
            for (int i = 0; i < 4; ++i)
#pragma unroll
                for (int j = 0; j < 4; ++j)
                    acc[i][j] = __builtin_amdgcn_mfma_f32_16x16x32_bf16(a[i], b[j], acc[i][j], 0, 0, 0);
        }
    }

    const int crow0 = (wave >> 1) * 64 + (lane >> 4) * 4;
    const int ccol0 = (wave & 1) * 64 + (lane & 15);
#pragma unroll
    for (int j = 0; j < 4; ++j) {
        int col = n0 + ccol0 + j * 16;
        float bb = bias[col];
#pragma unroll
        for (int i = 0; i < 4; ++i) {
            long row = m0 + crow0 + i * 16;
#pragma unroll
            for (int r = 0; r < 4; ++r) {
                float v = acc[i][j][r] + bb;
                if (ACT == 1) v = 0.5f * v * (1.0f + erff(v * 0.70710678118654752f));
                if (OF32) ((float*)Outv)[(row + r) * (long)ldo + col] = v;
                else      ((short*)Outv)[(row + r) * (long)ldo + col] = f2bf(v);
            }
        }
    }
}

// ---------------------------------------------------------------------------
// K column softmax stats (softmax over tokens per (b, channel)).
// ---------------------------------------------------------------------------
__global__ __launch_bounds__(256) void kstats_part(const short* __restrict__ QKV,
                                                   float* __restrict__ pm, float* __restrict__ ps)
{
    int b = blockIdx.y, ch = blockIdx.x, c = threadIdx.x;
    const short* Kp = QKV + ((long)b * NTOK_B + ch * 256) * 768 + 256 + c;
    float m = -1e30f, s = 0.0f;
    for (int n = 0; n < 256; ++n) {
        float x = bf2f(Kp[(long)n * 768]);
        if (x > m) { s = s * __expf(m - x) + 1.0f; m = x; }
        else       { s += __expf(x - m); }
    }
    pm[((long)b * 128 + ch) * 256 + c] = m;
    ps[((long)b * 128 + ch) * 256 + c] = s;
}

__global__ __launch_bounds__(256) void kstats_fin(const float* __restrict__ pm,
                                                  const float* __restrict__ ps,
                                                  float* __restrict__ kmax, float* __restrict__ ksum)
{
    int b = blockIdx.x, c = threadIdx.x;
    float m = -1e30f, s = 0.0f;
    for (int ch = 0; ch < 128; ++ch) {
        float mi = pm[((long)b * 128 + ch) * 256 + c];
        float si = ps[((long)b * 128 + ch) * 256 + c];
        if (mi > m) { s = s * __expf(m - mi) + si; m = mi; }
        else        { s += si * __expf(mi - m); }
    }
    kmax[b * 256 + c] = m;
    ksum[b * 256 + c] = s;
}

// ---------------------------------------------------------------------------
// context_raw[b][h][d][e] = sum_n exp(K[b,n,h*32+d]-kmax) * V[b,n,h*32+e]
// ---------------------------------------------------------------------------
__global__ __launch_bounds__(256) void context_k(const short* __restrict__ QKV,
                                                 const float* __restrict__ kmax,
                                                 float* __restrict__ ctx)
{
    int b = blockIdx.z, h = blockIdx.y;
    long tok0 = (long)b * NTOK_B + (long)blockIdx.x * 1024;
    __shared__ __align__(16) float kb[8][32], vb[8][32];
    __shared__ float smax[32];
    int tid = threadIdx.x;
    if (tid < 32) smax[tid] = kmax[b * 256 + h * 32 + tid];
    int d = tid >> 3, e0 = (tid & 7) * 4;
    int tl = tid >> 5, r = tid & 31;
    float a0 = 0, a1 = 0, a2 = 0, a3 = 0;
    for (int g = 0; g < 128; ++g) {
        __syncthreads();
        long trow = tok0 + g * 8 + tl;
        if (r < 16) {
            int dd = r * 2;
            const short* Kp = QKV + trow * 768 + 256 + h * 32 + dd;
            kb[tl][dd]     = __expf(bf2f(Kp[0]) - smax[dd]);
            kb[tl][dd + 1] = __expf(bf2f(Kp[1]) - smax[dd + 1]);
        } else {
            int ee = (r - 16) * 2;
            const short* Vp = QKV + trow * 768 + 512 + h * 32 + ee;
            vb[tl][ee]     = bf2f(Vp[0]);
            vb[tl][ee + 1] = bf2f(Vp[1]);
        }
        __syncthreads();
#pragma unroll
        for (int tt = 0; tt < 8; ++tt) {
            float kd = kb[tt][d];
            float4 v = *(const float4*)&vb[tt][e0];
            a0 += kd * v.x; a1 += kd * v.y; a2 += kd * v.z; a3 += kd * v.w;
        }
    }
    float* cp = ctx + (((long)b * 8 + h) * 32 + d) * 32 + e0;
    atomicAdd(cp + 0, a0); atomicAdd(cp + 1, a1);
    atomicAdd(cp + 2, a2); atomicAdd(cp + 3, a3);
}

// ---------------------------------------------------------------------------
// Fused: q softmax -> attn = q_norm @ (ctx/Z) -> + qin(fp32) -> LN1 -> bf16
// ---------------------------------------------------------------------------
__global__ __launch_bounds__(256) void attn_ln1(const short* __restrict__ QKV,
                                                const float* __restrict__ qin,
                                                const float* __restrict__ ctx,
                                                const float* __restrict__ ksum,
                                                const float* __restrict__ g1,
                                                const float* __restrict__ b1,
                                                short* __restrict__ xout)
{
    long tok0blk = (long)blockIdx.x * 128;
    int b = (int)(tok0blk >> 15);
    __shared__ __align__(16) float qn[16][292];
    __shared__ __align__(16) float xb[16][292];
    __shared__ float red[16][8][2];
    __shared__ float mr[16][2];
    int tid = threadIdx.x;
    int h = tid >> 5, e = tid & 31;

    float cregs[32];
    {
        const float* cp = ctx + ((long)(b * 8 + h) * 32) * 32 + e;
        const float* zs = ksum + b * 256 + h * 32;
#pragma unroll
        for (int d = 0; d < 32; ++d) cregs[d] = cp[d * 32] / zs[d];
    }

    for (int sub = 0; sub < 8; ++sub) {
        long tok0 = tok0blk + sub * 16;
        if (tid < 128) {
            int tA = tid >> 3, hA = tid & 7;
            const short* Qp = QKV + (tok0 + tA) * 768 + hA * 32;
            short qv[32];
            *(int4*)&qv[0]  = *(const int4*)(Qp);
            *(int4*)&qv[8]  = *(const int4*)(Qp + 8);
            *(int4*)&qv[16] = *(const int4*)(Qp + 16);
            *(int4*)&qv[24] = *(const int4*)(Qp + 24);
            float f[32]; float mx = -1e30f;
#pragma unroll
            for (int i = 0; i < 32; ++i) { f[i] = bf2f(qv[i]); mx = fmaxf(mx, f[i]); }
            float s = 0.0f;
#pragma unroll
            for (int i = 0; i < 32; ++i) { f[i] = __expf(f[i] - mx); s += f[i]; }
            float inv = 1.0f / s;
            float* qrow = &qn[tA][hA * 36];
#pragma unroll
            for (int i = 0; i < 32; ++i) qrow[i] = f[i] * inv;
        }
        __syncthreads();
        {
            int cch = h * 32 + e;
#pragma unroll 2
            for (int t = 0; t < 16; ++t) {
                const float4* qr = (const float4*)&qn[t][h * 36];
                float a = 0.0f;
#pragma unroll
                for (int d4 = 0; d4 < 8; ++d4) {
                    float4 qv = qr[d4];
                    a += qv.x * cregs[d4 * 4 + 0] + qv.y * cregs[d4 * 4 + 1]
                       + qv.z * cregs[d4 * 4 + 2] + qv.w * cregs[d4 * 4 + 3];
                }
                float iv = qin[(tok0 + t) * 256 + cch];
                xb[t][cch] = a + iv;
            }
        }
        __syncthreads();
        if (tid < 128) {
            int tC = tid & 15, sC = tid >> 4;
            float s = 0, ss = 0;
            const float* xr = &xb[tC][sC * 32];
#pragma unroll
            for (int i = 0; i < 32; ++i) { float v = xr[i]; s += v; ss += v * v; }
            red[tC][sC][0] = s; red[tC][sC][1] = ss;
        }
        __syncthreads();
        if (tid < 16) {
            float s = 0, ss = 0;
#pragma unroll
            for (int k = 0; k < 8; ++k) { s += red[tid][k][0]; ss += red[tid][k][1]; }
            float mean = s * (1.0f / 256.0f);
            float var  = ss * (1.0f / 256.0f) - mean * mean;
            mr[tid][0] = mean; mr[tid][1] = rsqrtf(var + LN_EPS);
        }
        __syncthreads();
        if (tid < 128) {
            int tC = tid & 15, sC = tid >> 4;
            float mean = mr[tC][0], rstd = mr[tC][1];
            const float* xr = &xb[tC][sC * 32];
            short ov[32];
#pragma unroll
            for (int i = 0; i < 32; ++i) {
                int c = sC * 32 + i;
                float v = (xr[i] - mean) * rstd * g1[c] + b1[c];
                ov[i] = f2bf(v);
            }
            int4* op = (int4*)(xout + (tok0 + tC) * 256 + sC * 32);
            op[0] = *(int4*)&ov[0];  op[1] = *(int4*)&ov[8];
            op[2] = *(int4*)&ov[16]; op[3] = *(int4*)&ov[24];
        }
        __syncthreads();
    }
}

// ---------------------------------------------------------------------------
// LN2 in-place on d_out (fp32): out = LN(x + y)
// ---------------------------------------------------------------------------
__global__ __launch_bounds__(256) void ln2_k(const short* __restrict__ xbuf,
                                             float* __restrict__ out,
                                             const float* __restrict__ g2,
                                             const float* __restrict__ b2)
{
    int wave = threadIdx.x >> 6, lane = threadIdx.x & 63;
    long tok = (long)blockIdx.x * 4 + wave;
    int c0 = lane * 4;
    const short* xp = xbuf + tok * 256 + c0;
    float* yp = out + tok * 256 + c0;
    short xv[4];
    *(int2*)xv = *(const int2*)xp;
    float4 yv = *(const float4*)yp;
    float v[4]; float s = 0, ss = 0;
    v[0] = bf2f(xv[0]) + yv.x; v[1] = bf2f(xv[1]) + yv.y;
    v[2] = bf2f(xv[2]) + yv.z; v[3] = bf2f(xv[3]) + yv.w;
#pragma unroll
    for (int i = 0; i < 4; ++i) { s += v[i]; ss += v[i] * v[i]; }
#pragma unroll
    for (int off = 32; off > 0; off >>= 1) { s += __shfl_xor(s, off); ss += __shfl_xor(ss, off); }
    float mean = s * (1.0f / 256.0f);
    float rstd = rsqrtf(ss * (1.0f / 256.0f) - mean * mean + LN_EPS);
    float4 ov;
    ov.x = (v[0] - mean) * rstd * g2[c0 + 0] + b2[c0 + 0];
    ov.y = (v[1] - mean) * rstd * g2[c0 + 1] + b2[c0 + 1];
    ov.z = (v[2] - mean) * rstd * g2[c0 + 2] + b2[c0 + 2];
    ov.w = (v[3] - mean) * rstd * g2[c0 + 3] + b2[c0 + 3];
    *(float4*)yp = ov;
}

// ---------------------------------------------------------------------------
extern "C" void kernel_launch(void* const* d_in, const int* in_sizes, int n_in,
                              void* d_out, int out_size, void* d_ws, size_t ws_size,
                              hipStream_t stream)
{
    const float* q    = (const float*)d_in[0];
    const float* kv   = (const float*)d_in[1];
    const float* wq_w = (const float*)d_in[2];
    const float* wq_b = (const float*)d_in[3];
    const float* wk_w = (const float*)d_in[4];
    const float* wk_b = (const float*)d_in[5];
    const float* wv_w = (const float*)d_in[6];
    const float* wv_b = (const float*)d_in[7];
    const float* ln1g = (const float*)d_in[8];
    const float* ln1b = (const float*)d_in[9];
    const float* ff1w = (const float*)d_in[10];
    const float* ff1b = (const float*)d_in[11];
    const float* ff2w = (const float*)d_in[12];
    const float* ff2b = (const float*)d_in[13];
    const float* ln2g = (const float*)d_in[14];
    const float* ln2b = (const float*)d_in[15];

    char* w = (char*)d_ws;
    short* Wtq  = (short*)w; w += 131072;          // [256][256] bf16
    short* Wtkv = (short*)w; w += 262144;          // [512][256] bf16 (K rows then V rows)
    short* Wt1  = (short*)w; w += 524288;          // [1024][256] bf16
    short* Wt2  = (short*)w; w += 524288;          // [256][1024] bf16
    float* bkv  = (float*)w; w += 2048;            // [512] f32 concat bias
    float* pm   = (float*)w; w += 262144;          // [2][128][256] f32
    float* ps   = (float*)w; w += 262144;
    float* kmx  = (float*)w; w += 2048;            // [2][256] f32
    float* ksm  = (float*)w; w += 2048;
    float* ctx  = (float*)w; w += 65536;           // [2][8][32][32] f32
    short* xbuf = (short*)w; w += 33554432;        // [65536][256] bf16; aliases kvb
    short* h1   = (short*)w; w += 134217728;       // [65536][1024] bf16
    short* QKV  = h1;                              // [65536][768] bf16 (dead before ff1)
    short* qb   = h1 + (long)TOK_TOT * 768;        // [65536][256] bf16 in h1 spare
    short* kvb  = xbuf;                            // kv bf16, dead before attn_ln1 writes
    float* y    = (float*)d_out;                   // ff2 out fp32, LN2 in-place

    // fp32 -> bf16 activations
    cvt_bf16_k<<<8192, 256, 0, stream>>>(q,  qb);
    cvt_bf16_k<<<8192, 256, 0, stream>>>(kv, kvb);

    dim3 tb(32, 8);
    transpose_k<<<dim3(8, 8),  tb, 0, stream>>>(wq_w, Wtq, 256, 256);
    transpose_k<<<dim3(8, 8),  tb, 0, stream>>>(wk_w, Wtkv, 256, 256);
    transpose_k<<<dim3(8, 8),  tb, 0, stream>>>(wv_w, Wtkv + 65536, 256, 256);
    transpose_k<<<dim3(8, 32), tb, 0, stream>>>(ff1w, Wt1, 256, 1024);
    transpose_k<<<dim3(32, 8), tb, 0, stream>>>(ff2w, Wt2, 1024, 256);
    concat_bias<<<1, 256, 0, stream>>>(wk_b, wv_b, bkv);

    // projections into interleaved [M][768]: Q at 0, K at 256, V at 512
    gemm_bt<0,0><<<dim3(2, 512), 256, 0, stream>>>(qb,  Wtq,  wq_b, QKV,       256, 256, 256, 768);
    gemm_bt<0,0><<<dim3(4, 512), 256, 0, stream>>>(kvb, Wtkv, bkv,  QKV + 256, 512, 256, 256, 768);

    kstats_part<<<dim3(128, 2), 256, 0, stream>>>(QKV, pm, ps);
    kstats_fin<<<2, 256, 0, stream>>>(pm, ps, kmx, ksm);

    hipMemsetAsync(ctx, 0, 65536, stream);
    context_k<<<dim3(32, 8, 2), 256, 0, stream>>>(QKV, kmx, ctx);

    attn_ln1<<<512, 256, 0, stream>>>(QKV, q, ctx, ksm, ln1g, ln1b, xbuf);

    gemm_bt<1,0><<<dim3(8, 512), 256, 0, stream>>>(xbuf, Wt1, ff1b, h1, 1024, 256, 256, 1024);
    gemm_bt<0,1><<<dim3(2, 512), 256, 0, stream>>>(h1,  Wt2, ff2b, y,  256, 1024, 1024, 256);

    ln2_k<<<16384, 256, 0, stream>>>(xbuf, y, ln2g, ln2b);
}